// Round 19
// baseline (128.641 us; speedup 1.0000x reference)
//
#include <hip/hip_runtime.h>

#define IO_DIM 64
#define WIDTH 16
#define HID 128
#define BS_ 1024                 // 64*16
#define NTH 256                  // 4 waves/block
#define GRID_PERSIST 512         // 2 blocks/CU (proven clean-traffic point)

// ws layout v2 (floats):
//   wT [64][16]  at    0..1024)   : wT[k][j] = w[j][k]
//   uT [64][16]  at 1024..2048)   : uT[d][j] = u[j][d] / 16
//   bb [16]      at 2048..2064)
//   nuw[16]      at 2064..2080)   : -uw[j] / 16

typedef __attribute__((ext_vector_type(4))) float f32x4;
typedef __attribute__((ext_vector_type(8))) short bf16x8;

union U4 { unsigned u[4]; bf16x8 v; };

__device__ __forceinline__ unsigned cvt_pk_bf16(float lo, float hi) {
    unsigned r;
    asm("v_cvt_pk_bf16_f32 %0, %1, %2" : "=v"(r) : "v"(lo), "v"(hi));
    return r;
}

__device__ __forceinline__ float fast_tanh(float x) {
    float e = __expf(2.0f * x);
    return 1.0f - __fdividef(2.0f, e + 1.0f);
}

// split 8 f32 into bf16 hi (RTNE) + bf16 lo (residual) fragments
__device__ __forceinline__ void split8(const float* x, bf16x8& hi, bf16x8& lo) {
    U4 H, L;
    #pragma unroll
    for (int i = 0; i < 4; ++i) {
        unsigned h = cvt_pk_bf16(x[2 * i], x[2 * i + 1]);
        float h0 = __uint_as_float(h << 16);
        float h1 = __uint_as_float(h & 0xffff0000u);
        H.u[i] = h;
        L.u[i] = cvt_pk_bf16(x[2 * i] - h0, x[2 * i + 1] - h1);
    }
    hi = H.v; lo = L.v;
}

__global__ __launch_bounds__(128) void cnf_prep(
    const float* __restrict__ t, const float* __restrict__ W1,
    const float* __restrict__ b1, const float* __restrict__ W2,
    const float* __restrict__ b2, const float* __restrict__ W3,
    const float* __restrict__ b3, float* __restrict__ ws)
{
    __shared__ float h1[HID];
    __shared__ float h2[HID];
    __shared__ float su[64], sw[64];
    const int tid = threadIdx.x;

    h1[tid] = tanhf(W1[tid] * t[0] + b1[tid]);
    __syncthreads();

    {
        float s = b2[tid];
        const float4* W2v = (const float4*)(W2 + tid * HID);
        #pragma unroll 8
        for (int k = 0; k < HID / 4; ++k) {
            float4 wv = W2v[k];
            s = fmaf(wv.x, h1[4 * k + 0], s);
            s = fmaf(wv.y, h1[4 * k + 1], s);
            s = fmaf(wv.z, h1[4 * k + 2], s);
            s = fmaf(wv.w, h1[4 * k + 3], s);
        }
        h2[tid] = tanhf(s);
    }
    __syncthreads();

    const int b = blockIdx.x;
    if (b < 16) {
        const int half = tid >> 6;   // 0 -> u, 1 -> w
        const int i = tid & 63;      // element index (d or k)
        const int row = half * BS_ + b * 64 + i;
        float s = b3[row];
        const float4* W3v = (const float4*)(W3 + row * HID);
        #pragma unroll 8
        for (int k = 0; k < HID / 4; ++k) {
            float4 wv = W3v[k];
            s = fmaf(wv.x, h2[4 * k + 0], s);
            s = fmaf(wv.y, h2[4 * k + 1], s);
            s = fmaf(wv.z, h2[4 * k + 2], s);
            s = fmaf(wv.w, h2[4 * k + 3], s);
        }
        if (half == 0) {
            ws[1024 + i * 16 + b] = s * (1.0f / WIDTH);   // uT[d][j], scale folded
            su[i] = s;
        } else {
            ws[i * 16 + b] = s;                           // wT[k][j]
            sw[i] = s;
        }
        __syncthreads();
        if (tid < 64) {
            float p = su[tid] * sw[tid];
            #pragma unroll
            for (int m = 32; m >= 1; m >>= 1) p += __shfl_xor(p, m, 64);
            if (tid == 0) ws[2064 + b] = -p * (1.0f / WIDTH);   // nuw[b]
        }
    } else {
        if (tid < WIDTH) {
            const int row = 2 * BS_ + tid;
            float s = b3[row];
            const float4* W3v = (const float4*)(W3 + row * HID);
            #pragma unroll 8
            for (int k = 0; k < HID / 4; ++k) {
                float4 wv = W3v[k];
                s = fmaf(wv.x, h2[4 * k + 0], s);
                s = fmaf(wv.y, h2[4 * k + 1], s);
                s = fmaf(wv.z, h2[4 * k + 2], s);
                s = fmaf(wv.w, h2[4 * k + 3], s);
            }
            ws[2048 + tid] = s;   // bb
        }
    }
}

// LDS scratch slot for (row r in [0,16), float4 c in [0,8)) — bijective,
// bank-floor-even on both the coalesced write and the fragment read:
//   slot(r,c) = r*8 + ((c>>2)^(r&1))*4 + ((c&3)^((r>>1)&3))
__device__ __forceinline__ int scr_slot(int r, int c) {
    return r * 8 + (((c >> 2) ^ (r & 1)) << 2) + ((c & 3) ^ ((r >> 1) & 3));
}

// coalesced tile load: instruction (h,g,s) covers 16 rows x 64 B
// (lane l -> row g*16+(l>>2), float4 h*8+s*4+(l&3)); the s-pair completes
// each row's 128-B line, fetched once.
__device__ __forceinline__ void load_tile(const float4* __restrict__ zg,
                                          int wbase, int n, int l,
                                          float4 (&v)[2][4][2])
{
    const int rr = l >> 2;
    const int cc = l & 3;
    #pragma unroll
    for (int h = 0; h < 2; ++h) {
        #pragma unroll
        for (int g = 0; g < 4; ++g) {
            const int row = min(wbase + g * 16 + rr, n - 1);
            #pragma unroll
            for (int s = 0; s < 2; ++s)
                v[h][g][s] = zg[(size_t)row * 16 + h * 8 + s * 4 + cc];
        }
    }
}

// Persistent MFMA main kernel: r14 structure (depth-1 rotating prefetch,
// dt-pair stores, grid 512) with COALESCED z loads bounced through a 2 KB
// wave-private LDS scratch (zero barriers: same-wave DS is in-order, r5-8).
__global__ __launch_bounds__(NTH, 2) void cnf_main(
    const float* __restrict__ z, const float* __restrict__ ws,
    float* __restrict__ dz, float* __restrict__ dlog, int n)
{
    __shared__ __align__(16) float4 scr[4][16][8];   // 2 KB per wave

    const int tid = threadIdx.x;
    const int wv  = tid >> 6;
    const int l   = tid & 63;
    const int q   = l >> 4;          // lane quadrant
    const int r15 = l & 15;

    // ---- pinned weight fragments (loaded once per wave lifetime) ----
    bf16x8 whi[2], wlo[2];
    #pragma unroll
    for (int h = 0; h < 2; ++h) {
        float w8[8];
        #pragma unroll
        for (int e = 0; e < 8; ++e)
            w8[e] = ws[(h * 32 + q * 8 + e) * 16 + r15];
        split8(w8, whi[h], wlo[h]);
    }
    bf16x8 uhi[4], ulo[4];
    #pragma unroll
    for (int dt = 0; dt < 4; ++dt) {
        float u8[8];
        #pragma unroll
        for (int e = 0; e < 8; ++e)
            u8[e] = (q < 2) ? ws[1024 + (dt * 16 + r15) * 16 + q * 8 + e] : 0.0f;
        split8(u8, uhi[dt], ulo[dt]);
    }
    f32x4 bbv; float nuwv[4];
    #pragma unroll
    for (int rr = 0; rr < 4; ++rr) {
        bbv[rr]  = ws[2048 + q * 4 + rr];   // bb[j], j = 4q+rr
        nuwv[rr] = ws[2064 + q * 4 + rr];
    }

    const int ntiles = (n + 63) >> 6;
    const int nw = gridDim.x * (NTH / 64);          // total waves
    int tile = blockIdx.x * (NTH / 64) + wv;
    if (tile >= ntiles) return;

    const float4* zg = (const float4*)z;
    float4* dzv = (float4*)dz;
    const int sbase = ((2 * q) & 3) * 16 + r15;     // q>=2: dummy (masked)

    // write-side scratch slots (lane is (rw = l>>2, cw = s*4 + (l&3)))
    const int rw = l >> 2;
    const int w_slot0 = scr_slot(rw, (l & 3));       // s = 0
    const int w_slot1 = scr_slot(rw, 4 + (l & 3));   // s = 1
    // read-side slots (lane needs row r15, chunks q*2, q*2+1)
    const int r_slotA = scr_slot(r15, 2 * q);
    const int r_slotB = scr_slot(r15, 2 * q + 1);
    float4* sw_ = &scr[wv][0][0];

    // ---- initial tile load (16 coalesced dwordx4) ----
    float4 v[2][4][2];
    load_tile(zg, tile * 64, n, l, v);

    for (;;) {
        const int wbase = tile * 64;
        const int nt = tile + nw;

        // ---- phase 1: bounce each (h,g) 2 KB block through LDS to restore
        // fragment layout, then 3 MFMAs (math identical to r14) ----
        f32x4 acc[4];
        #pragma unroll
        for (int g = 0; g < 4; ++g) acc[g] = bbv;

        #pragma unroll
        for (int h = 0; h < 2; ++h) {
            #pragma unroll
            for (int g = 0; g < 4; ++g) {
                sw_[w_slot0] = v[h][g][0];
                sw_[w_slot1] = v[h][g][1];
                const float4 a4 = sw_[r_slotA];
                const float4 b4 = sw_[r_slotB];
                float z8[8] = {a4.x, a4.y, a4.z, a4.w, b4.x, b4.y, b4.z, b4.w};
                bf16x8 zhi, zlo; split8(z8, zhi, zlo);
                acc[g] = __builtin_amdgcn_mfma_f32_16x16x32_bf16(whi[h], zhi, acc[g], 0, 0, 0);
                acc[g] = __builtin_amdgcn_mfma_f32_16x16x32_bf16(wlo[h], zhi, acc[g], 0, 0, 0);
                acc[g] = __builtin_amdgcn_mfma_f32_16x16x32_bf16(whi[h], zlo, acc[g], 0, 0, 0);
            }
        }

        // ---- prefetch next tile into the (now dead) v registers ----
        if (nt < ntiles)
            load_tile(zg, nt * 64, n, l, v);

        // ---- phase 2 + outputs, per 16-row group (unchanged from r14) ----
        float trs[4];
        #pragma unroll
        for (int g = 0; g < 4; ++g) {
            const float t0 = fast_tanh(acc[g][0]);
            const float t1 = fast_tanh(acc[g][1]);
            const float t2 = fast_tanh(acc[g][2]);
            const float t3 = fast_tanh(acc[g][3]);

            float tr = (1.0f - t0 * t0) * nuwv[0];
            tr = fmaf(1.0f - t1 * t1, nuwv[1], tr);
            tr = fmaf(1.0f - t2 * t2, nuwv[2], tr);
            tr = fmaf(1.0f - t3 * t3, nuwv[3], tr);
            tr += __shfl_xor(tr, 16);
            tr += __shfl_xor(tr, 32);
            trs[g] = tr;

            // th -> B-frag: lane needs th[j = q*8+e][r15] from quadrants 2q, 2q+1
            const int pk01 = (int)cvt_pk_bf16(t0, t1);
            const int pk23 = (int)cvt_pk_bf16(t2, t3);
            const int w0 = __shfl(pk01, sbase);
            const int w1 = __shfl(pk23, sbase);
            const int w2 = __shfl(pk01, sbase + 16);
            const int w3 = __shfl(pk23, sbase + 16);
            const bool act = (q < 2);
            U4 B;
            B.u[0] = act ? (unsigned)w0 : 0u;
            B.u[1] = act ? (unsigned)w1 : 0u;
            B.u[2] = act ? (unsigned)w2 : 0u;
            B.u[3] = act ? (unsigned)w3 : 0u;
            const bf16x8 b2 = B.v;

            f32x4 o[4];
            #pragma unroll
            for (int dt = 0; dt < 4; ++dt) {
                f32x4 zz = {0.f, 0.f, 0.f, 0.f};
                zz    = __builtin_amdgcn_mfma_f32_16x16x32_bf16(ulo[dt], b2, zz, 0, 0, 0);
                o[dt] = __builtin_amdgcn_mfma_f32_16x16x32_bf16(uhi[dt], b2, zz, 0, 0, 0);
            }
            // stores: lane holds dz[row = wbase+g*16+r15][d = dt*16+4q .. +3]
            const int grow = wbase + g * 16 + r15;
            if (grow < n) {
                #pragma unroll
                for (int dt = 0; dt < 4; ++dt) {
                    float4 s4 = make_float4(o[dt][0], o[dt][1], o[dt][2], o[dt][3]);
                    dzv[(size_t)grow * 16 + dt * 4 + q] = s4;
                }
            }
        }

        // dlog: lane l -> group q, in-group row r15
        float trf = trs[0];
        trf = (q == 1) ? trs[1] : trf;
        trf = (q == 2) ? trs[2] : trf;
        trf = (q == 3) ? trs[3] : trf;
        if (wbase + l < n) dlog[wbase + l] = trf;

        if (nt >= ntiles) break;
        tile = nt;
    }
}

extern "C" void kernel_launch(void* const* d_in, const int* in_sizes, int n_in,
                              void* d_out, int out_size, void* d_ws, size_t ws_size,
                              hipStream_t stream) {
    const float* t  = (const float*)d_in[0];
    const float* z  = (const float*)d_in[1];
    const float* W1 = (const float*)d_in[2];
    const float* b1 = (const float*)d_in[3];
    const float* W2 = (const float*)d_in[4];
    const float* b2 = (const float*)d_in[5];
    const float* W3 = (const float*)d_in[6];
    const float* b3 = (const float*)d_in[7];

    const int n = in_sizes[1] / IO_DIM;   // 500000
    float* ws   = (float*)d_ws;
    float* out  = (float*)d_out;
    float* dzp  = out;
    float* dlog = out + (size_t)n * IO_DIM;

    cnf_prep<<<17, 128, 0, stream>>>(t, W1, b1, W2, b2, W3, b3, ws);

    const int ntiles = (n + 63) >> 6;
    int grid = GRID_PERSIST;
    const int max_blocks = (ntiles + (NTH / 64) - 1) / (NTH / 64);
    if (grid > max_blocks) grid = max_blocks;
    cnf_main<<<grid, NTH, 0, stream>>>(z, ws, dzp, dlog, n);
}

// Round 20
// 65.420 us; speedup vs baseline: 1.9664x; 1.9664x over previous
//
#include <hip/hip_runtime.h>

#define IO_DIM 64
#define WIDTH 16
#define HID 128
#define BS_ 1024                 // 64*16
#define NTH 256                  // 4 waves/block

// ws layout v2 (floats):
//   wT [64][16]  at    0..1024)   : wT[k][j] = w[j][k]
//   uT [64][16]  at 1024..2048)   : uT[d][j] = u[j][d] / 16
//   bb [16]      at 2048..2064)
//   nuw[16]      at 2064..2080)   : -uw[j] / 16

typedef __attribute__((ext_vector_type(4))) float f32x4;
typedef __attribute__((ext_vector_type(8))) short bf16x8;

union U4 { unsigned u[4]; bf16x8 v; };

__device__ __forceinline__ unsigned cvt_pk_bf16(float lo, float hi) {
    unsigned r;
    asm("v_cvt_pk_bf16_f32 %0, %1, %2" : "=v"(r) : "v"(lo), "v"(hi));
    return r;
}

__device__ __forceinline__ float fast_tanh(float x) {
    float e = __expf(2.0f * x);
    return 1.0f - __fdividef(2.0f, e + 1.0f);
}

// split 8 f32 into bf16 hi (RTNE) + bf16 lo (residual) fragments
__device__ __forceinline__ void split8(const float* x, bf16x8& hi, bf16x8& lo) {
    U4 H, L;
    #pragma unroll
    for (int i = 0; i < 4; ++i) {
        unsigned h = cvt_pk_bf16(x[2 * i], x[2 * i + 1]);
        float h0 = __uint_as_float(h << 16);
        float h1 = __uint_as_float(h & 0xffff0000u);
        H.u[i] = h;
        L.u[i] = cvt_pk_bf16(x[2 * i] - h0, x[2 * i + 1] - h1);
    }
    hi = H.v; lo = L.v;
}

__global__ __launch_bounds__(128) void cnf_prep(
    const float* __restrict__ t, const float* __restrict__ W1,
    const float* __restrict__ b1, const float* __restrict__ W2,
    const float* __restrict__ b2, const float* __restrict__ W3,
    const float* __restrict__ b3, float* __restrict__ ws)
{
    __shared__ float h1[HID];
    __shared__ float h2[HID];
    __shared__ float su[64], sw[64];
    const int tid = threadIdx.x;

    h1[tid] = tanhf(W1[tid] * t[0] + b1[tid]);
    __syncthreads();

    {
        float s = b2[tid];
        const float4* W2v = (const float4*)(W2 + tid * HID);
        #pragma unroll 8
        for (int k = 0; k < HID / 4; ++k) {
            float4 wv = W2v[k];
            s = fmaf(wv.x, h1[4 * k + 0], s);
            s = fmaf(wv.y, h1[4 * k + 1], s);
            s = fmaf(wv.z, h1[4 * k + 2], s);
            s = fmaf(wv.w, h1[4 * k + 3], s);
        }
        h2[tid] = tanhf(s);
    }
    __syncthreads();

    const int b = blockIdx.x;
    if (b < 16) {
        const int half = tid >> 6;   // 0 -> u, 1 -> w
        const int i = tid & 63;      // element index (d or k)
        const int row = half * BS_ + b * 64 + i;
        float s = b3[row];
        const float4* W3v = (const float4*)(W3 + row * HID);
        #pragma unroll 8
        for (int k = 0; k < HID / 4; ++k) {
            float4 wv = W3v[k];
            s = fmaf(wv.x, h2[4 * k + 0], s);
            s = fmaf(wv.y, h2[4 * k + 1], s);
            s = fmaf(wv.z, h2[4 * k + 2], s);
            s = fmaf(wv.w, h2[4 * k + 3], s);
        }
        if (half == 0) {
            ws[1024 + i * 16 + b] = s * (1.0f / WIDTH);   // uT[d][j], scale folded
            su[i] = s;
        } else {
            ws[i * 16 + b] = s;                           // wT[k][j]
            sw[i] = s;
        }
        __syncthreads();
        if (tid < 64) {
            float p = su[tid] * sw[tid];
            #pragma unroll
            for (int m = 32; m >= 1; m >>= 1) p += __shfl_xor(p, m, 64);
            if (tid == 0) ws[2064 + b] = -p * (1.0f / WIDTH);   // nuw[b]
        }
    } else {
        if (tid < WIDTH) {
            const int row = 2 * BS_ + tid;
            float s = b3[row];
            const float4* W3v = (const float4*)(W3 + row * HID);
            #pragma unroll 8
            for (int k = 0; k < HID / 4; ++k) {
                float4 wv = W3v[k];
                s = fmaf(wv.x, h2[4 * k + 0], s);
                s = fmaf(wv.y, h2[4 * k + 1], s);
                s = fmaf(wv.z, h2[4 * k + 2], s);
                s = fmaf(wv.w, h2[4 * k + 3], s);
            }
            ws[2048 + tid] = s;   // bb
        }
    }
}

// Semi-persistent MFMA main kernel, zero LDS, rotating z prefetch.
// Identical to the round-14 kernel; only the launch grid changed so each
// wave handles exactly TWO tiles (preamble amortized, tile-2 latency hidden,
// streams time-separated like the non-persistent r12 -> clean L2 merging).
__global__ __launch_bounds__(NTH, 2) void cnf_main(
    const float* __restrict__ z, const float* __restrict__ ws,
    float* __restrict__ dz, float* __restrict__ dlog, int n)
{
    const int tid = threadIdx.x;
    const int wv  = tid >> 6;
    const int l   = tid & 63;
    const int q   = l >> 4;          // lane quadrant
    const int r15 = l & 15;

    // ---- pinned weight fragments (loaded once per wave lifetime) ----
    bf16x8 whi[2], wlo[2];
    #pragma unroll
    for (int h = 0; h < 2; ++h) {
        float w8[8];
        #pragma unroll
        for (int e = 0; e < 8; ++e)
            w8[e] = ws[(h * 32 + q * 8 + e) * 16 + r15];
        split8(w8, whi[h], wlo[h]);
    }
    bf16x8 uhi[4], ulo[4];
    #pragma unroll
    for (int dt = 0; dt < 4; ++dt) {
        float u8[8];
        #pragma unroll
        for (int e = 0; e < 8; ++e)
            u8[e] = (q < 2) ? ws[1024 + (dt * 16 + r15) * 16 + q * 8 + e] : 0.0f;
        split8(u8, uhi[dt], ulo[dt]);
    }
    f32x4 bbv; float nuwv[4];
    #pragma unroll
    for (int rr = 0; rr < 4; ++rr) {
        bbv[rr]  = ws[2048 + q * 4 + rr];   // bb[j], j = 4q+rr
        nuwv[rr] = ws[2064 + q * 4 + rr];
    }

    const int ntiles = (n + 63) >> 6;
    const int nw = gridDim.x * (NTH / 64);          // total waves
    int tile = blockIdx.x * (NTH / 64) + wv;
    if (tile >= ntiles) return;

    const float4* zg = (const float4*)z;
    float4* dzv = (float4*)dz;
    const int sbase = ((2 * q) & 3) * 16 + r15;     // q>=2: dummy (masked)

    // ---- initial tile load (16 independent dwordx4) ----
    float4 zA[2][4], zB[2][4];
    {
        const int wbase = tile * 64;
        #pragma unroll
        for (int h = 0; h < 2; ++h) {
            #pragma unroll
            for (int g = 0; g < 4; ++g) {
                const int grow = min(wbase + g * 16 + r15, n - 1);
                const float4* p = zg + (size_t)grow * 16 + h * 8 + q * 2;
                zA[h][g] = p[0];
                zB[h][g] = p[1];
            }
        }
    }

    for (;;) {
        const int wbase = tile * 64;
        const int nt = tile + nw;

        // ---- phase 1: a^T[j][r] = sum_k w[j][k] z[r][k] + bb[j] ----
        f32x4 acc[4];
        #pragma unroll
        for (int g = 0; g < 4; ++g) acc[g] = bbv;

        #pragma unroll
        for (int h = 0; h < 2; ++h) {
            #pragma unroll
            for (int g = 0; g < 4; ++g) {
                const float4 a4 = zA[h][g], b4 = zB[h][g];
                float z8[8] = {a4.x, a4.y, a4.z, a4.w, b4.x, b4.y, b4.z, b4.w};
                bf16x8 zhi, zlo; split8(z8, zhi, zlo);
                acc[g] = __builtin_amdgcn_mfma_f32_16x16x32_bf16(whi[h], zhi, acc[g], 0, 0, 0);
                acc[g] = __builtin_amdgcn_mfma_f32_16x16x32_bf16(wlo[h], zhi, acc[g], 0, 0, 0);
                acc[g] = __builtin_amdgcn_mfma_f32_16x16x32_bf16(whi[h], zlo, acc[g], 0, 0, 0);
            }
        }

        // ---- prefetch next tile into the (now dead) z registers ----
        if (nt < ntiles) {
            const int nb = nt * 64;
            #pragma unroll
            for (int h = 0; h < 2; ++h) {
                #pragma unroll
                for (int g = 0; g < 4; ++g) {
                    const int grow = min(nb + g * 16 + r15, n - 1);
                    const float4* p = zg + (size_t)grow * 16 + h * 8 + q * 2;
                    zA[h][g] = p[0];
                    zB[h][g] = p[1];
                }
            }
        }

        // ---- phase 2 + outputs, per 16-row group ----
        float trs[4];
        #pragma unroll
        for (int g = 0; g < 4; ++g) {
            const float t0 = fast_tanh(acc[g][0]);
            const float t1 = fast_tanh(acc[g][1]);
            const float t2 = fast_tanh(acc[g][2]);
            const float t3 = fast_tanh(acc[g][3]);

            float tr = (1.0f - t0 * t0) * nuwv[0];
            tr = fmaf(1.0f - t1 * t1, nuwv[1], tr);
            tr = fmaf(1.0f - t2 * t2, nuwv[2], tr);
            tr = fmaf(1.0f - t3 * t3, nuwv[3], tr);
            tr += __shfl_xor(tr, 16);
            tr += __shfl_xor(tr, 32);
            trs[g] = tr;

            // th -> B-frag: lane needs th[j = q*8+e][r15] from quadrants 2q, 2q+1
            const int pk01 = (int)cvt_pk_bf16(t0, t1);
            const int pk23 = (int)cvt_pk_bf16(t2, t3);
            const int w0 = __shfl(pk01, sbase);
            const int w1 = __shfl(pk23, sbase);
            const int w2 = __shfl(pk01, sbase + 16);
            const int w3 = __shfl(pk23, sbase + 16);
            const bool act = (q < 2);
            U4 B;
            B.u[0] = act ? (unsigned)w0 : 0u;
            B.u[1] = act ? (unsigned)w1 : 0u;
            B.u[2] = act ? (unsigned)w2 : 0u;
            B.u[3] = act ? (unsigned)w3 : 0u;
            const bf16x8 b2 = B.v;

            f32x4 o[4];
            #pragma unroll
            for (int dt = 0; dt < 4; ++dt) {
                f32x4 zz = {0.f, 0.f, 0.f, 0.f};
                zz    = __builtin_amdgcn_mfma_f32_16x16x32_bf16(ulo[dt], b2, zz, 0, 0, 0);
                o[dt] = __builtin_amdgcn_mfma_f32_16x16x32_bf16(uhi[dt], b2, zz, 0, 0, 0);
            }
            // stores: lane holds dz[row = wbase+g*16+r15][d = dt*16+4q .. +3]
            const int grow = wbase + g * 16 + r15;
            if (grow < n) {
                #pragma unroll
                for (int dt = 0; dt < 4; ++dt) {
                    float4 s = make_float4(o[dt][0], o[dt][1], o[dt][2], o[dt][3]);
                    dzv[(size_t)grow * 16 + dt * 4 + q] = s;
                }
            }
        }

        // dlog: lane l -> group q, in-group row r15
        float trf = trs[0];
        trf = (q == 1) ? trs[1] : trf;
        trf = (q == 2) ? trs[2] : trf;
        trf = (q == 3) ? trs[3] : trf;
        if (wbase + l < n) dlog[wbase + l] = trf;

        if (nt >= ntiles) break;
        tile = nt;
    }
}

extern "C" void kernel_launch(void* const* d_in, const int* in_sizes, int n_in,
                              void* d_out, int out_size, void* d_ws, size_t ws_size,
                              hipStream_t stream) {
    const float* t  = (const float*)d_in[0];
    const float* z  = (const float*)d_in[1];
    const float* W1 = (const float*)d_in[2];
    const float* b1 = (const float*)d_in[3];
    const float* W2 = (const float*)d_in[4];
    const float* b2 = (const float*)d_in[5];
    const float* W3 = (const float*)d_in[6];
    const float* b3 = (const float*)d_in[7];

    const int n = in_sizes[1] / IO_DIM;   // 500000
    float* ws   = (float*)d_ws;
    float* out  = (float*)d_out;
    float* dzp  = out;
    float* dlog = out + (size_t)n * IO_DIM;

    cnf_prep<<<17, 128, 0, stream>>>(t, W1, b1, W2, b2, W3, b3, ws);

    const int ntiles = (n + 63) >> 6;              // 7813
    // 2 tiles per wave: grid = ceil(ntiles / (waves_per_block * 2))
    const int grid = (ntiles + (NTH / 64) * 2 - 1) / ((NTH / 64) * 2);   // 977
    cnf_main<<<grid, NTH, 0, stream>>>(z, ws, dzp, dlog, n);
}

// Round 21
// 56.263 us; speedup vs baseline: 2.2864x; 1.1628x over previous
//
#include <hip/hip_runtime.h>

#define IO_DIM 64
#define WIDTH 16
#define HID 128
#define BS_ 1024                 // 64*16
#define NTH 256                  // 4 waves/block
#define GRID_PERSIST 512         // 2 blocks/CU (proven clean-traffic point)

// ws layout v2 (floats):
//   wT [64][16]  at    0..1024)   : wT[kslot][j] = w[j][kfloat(kslot)]  (K-permuted)
//   uT [64][16]  at 1024..2048)   : uT[d][j] = u[j][d] / 16
//   bb [16]      at 2048..2064)
//   nuw[16]      at 2064..2080)   : -uw[j] / 16
//
// K permutation: fragment slot (h,q,e) holds z float:
//   e<4 : chunk 8h+q  , float e       (zA: lanes q=0..3 -> consecutive chunks = one 64B sector)
//   e>=4: chunk 8h+4+q, float e-4     (zB: same)
// Inverse (float i -> slot): c7=(i>>2)&7; slot=(i>>5)*32+(c7&3)*8+((c7>>2)<<2)+(i&3)

typedef __attribute__((ext_vector_type(4))) float f32x4;
typedef __attribute__((ext_vector_type(8))) short bf16x8;

union U4 { unsigned u[4]; bf16x8 v; };

__device__ __forceinline__ unsigned cvt_pk_bf16(float lo, float hi) {
    unsigned r;
    asm("v_cvt_pk_bf16_f32 %0, %1, %2" : "=v"(r) : "v"(lo), "v"(hi));
    return r;
}

__device__ __forceinline__ float fast_tanh(float x) {
    float e = __expf(2.0f * x);
    return 1.0f - __fdividef(2.0f, e + 1.0f);
}

// split 8 f32 into bf16 hi (RTNE) + bf16 lo (residual) fragments
__device__ __forceinline__ void split8(const float* x, bf16x8& hi, bf16x8& lo) {
    U4 H, L;
    #pragma unroll
    for (int i = 0; i < 4; ++i) {
        unsigned h = cvt_pk_bf16(x[2 * i], x[2 * i + 1]);
        float h0 = __uint_as_float(h << 16);
        float h1 = __uint_as_float(h & 0xffff0000u);
        H.u[i] = h;
        L.u[i] = cvt_pk_bf16(x[2 * i] - h0, x[2 * i + 1] - h1);
    }
    hi = H.v; lo = L.v;
}

__global__ __launch_bounds__(128) void cnf_prep(
    const float* __restrict__ t, const float* __restrict__ W1,
    const float* __restrict__ b1, const float* __restrict__ W2,
    const float* __restrict__ b2, const float* __restrict__ W3,
    const float* __restrict__ b3, float* __restrict__ ws)
{
    __shared__ float h1[HID];
    __shared__ float h2[HID];
    __shared__ float su[64], sw[64];
    const int tid = threadIdx.x;

    h1[tid] = tanhf(W1[tid] * t[0] + b1[tid]);
    __syncthreads();

    {
        float s = b2[tid];
        const float4* W2v = (const float4*)(W2 + tid * HID);
        #pragma unroll 8
        for (int k = 0; k < HID / 4; ++k) {
            float4 wv = W2v[k];
            s = fmaf(wv.x, h1[4 * k + 0], s);
            s = fmaf(wv.y, h1[4 * k + 1], s);
            s = fmaf(wv.z, h1[4 * k + 2], s);
            s = fmaf(wv.w, h1[4 * k + 3], s);
        }
        h2[tid] = tanhf(s);
    }
    __syncthreads();

    const int b = blockIdx.x;
    if (b < 16) {
        const int half = tid >> 6;   // 0 -> u, 1 -> w
        const int i = tid & 63;      // element index (d or k-float)
        const int row = half * BS_ + b * 64 + i;
        float s = b3[row];
        const float4* W3v = (const float4*)(W3 + row * HID);
        #pragma unroll 8
        for (int k = 0; k < HID / 4; ++k) {
            float4 wv = W3v[k];
            s = fmaf(wv.x, h2[4 * k + 0], s);
            s = fmaf(wv.y, h2[4 * k + 1], s);
            s = fmaf(wv.z, h2[4 * k + 2], s);
            s = fmaf(wv.w, h2[4 * k + 3], s);
        }
        if (half == 0) {
            ws[1024 + i * 16 + b] = s * (1.0f / WIDTH);   // uT[d][j], scale folded
            su[i] = s;
        } else {
            // K-permuted wT: float i -> slot
            const int c7 = (i >> 2) & 7;
            const int slot = (i >> 5) * 32 + (c7 & 3) * 8 + ((c7 >> 2) << 2) + (i & 3);
            ws[slot * 16 + b] = s;                        // wT[kslot][j]
            sw[i] = s;
        }
        __syncthreads();
        if (tid < 64) {
            float p = su[tid] * sw[tid];
            #pragma unroll
            for (int m = 32; m >= 1; m >>= 1) p += __shfl_xor(p, m, 64);
            if (tid == 0) ws[2064 + b] = -p * (1.0f / WIDTH);   // nuw[b]
        }
    } else {
        if (tid < WIDTH) {
            const int row = 2 * BS_ + tid;
            float s = b3[row];
            const float4* W3v = (const float4*)(W3 + row * HID);
            #pragma unroll 8
            for (int k = 0; k < HID / 4; ++k) {
                float4 wv = W3v[k];
                s = fmaf(wv.x, h2[4 * k + 0], s);
                s = fmaf(wv.y, h2[4 * k + 1], s);
                s = fmaf(wv.z, h2[4 * k + 2], s);
                s = fmaf(wv.w, h2[4 * k + 3], s);
            }
            ws[2048 + tid] = s;   // bb
        }
    }
}

// Persistent MFMA main kernel, zero LDS, rotating z prefetch (r14 structure).
// Round 21: K-permuted z loads — each load instruction's 4 q-lanes read one
// CONTIGUOUS 64-B sector per row (was 2 half-used sectors) -> read-path
// sector-transactions halve. Math identical (wT permuted to match).
__global__ __launch_bounds__(NTH, 2) void cnf_main(
    const float* __restrict__ z, const float* __restrict__ ws,
    float* __restrict__ dz, float* __restrict__ dlog, int n)
{
    const int tid = threadIdx.x;
    const int wv  = tid >> 6;
    const int l   = tid & 63;
    const int q   = l >> 4;          // lane quadrant
    const int r15 = l & 15;

    // ---- pinned weight fragments (loaded once per wave lifetime) ----
    bf16x8 whi[2], wlo[2];
    #pragma unroll
    for (int h = 0; h < 2; ++h) {
        float w8[8];
        #pragma unroll
        for (int e = 0; e < 8; ++e)
            w8[e] = ws[(h * 32 + q * 8 + e) * 16 + r15];   // permuted slots baked in
        split8(w8, whi[h], wlo[h]);
    }
    bf16x8 uhi[4], ulo[4];
    #pragma unroll
    for (int dt = 0; dt < 4; ++dt) {
        float u8[8];
        #pragma unroll
        for (int e = 0; e < 8; ++e)
            u8[e] = (q < 2) ? ws[1024 + (dt * 16 + r15) * 16 + q * 8 + e] : 0.0f;
        split8(u8, uhi[dt], ulo[dt]);
    }
    f32x4 bbv; float nuwv[4];
    #pragma unroll
    for (int rr = 0; rr < 4; ++rr) {
        bbv[rr]  = ws[2048 + q * 4 + rr];   // bb[j], j = 4q+rr
        nuwv[rr] = ws[2064 + q * 4 + rr];
    }

    const int ntiles = (n + 63) >> 6;
    const int nw = gridDim.x * (NTH / 64);          // total waves
    int tile = blockIdx.x * (NTH / 64) + wv;
    if (tile >= ntiles) return;

    const float4* zg = (const float4*)z;
    float4* dzv = (float4*)dz;
    const int sbase = ((2 * q) & 3) * 16 + r15;     // q>=2: dummy (masked)

    // ---- initial tile load: zA = chunk 8h+q, zB = chunk 8h+4+q ----
    float4 zA[2][4], zB[2][4];
    {
        const int wbase = tile * 64;
        #pragma unroll
        for (int h = 0; h < 2; ++h) {
            #pragma unroll
            for (int g = 0; g < 4; ++g) {
                const int grow = min(wbase + g * 16 + r15, n - 1);
                const float4* p = zg + (size_t)grow * 16 + h * 8 + q;
                zA[h][g] = p[0];
                zB[h][g] = p[4];
            }
        }
    }

    for (;;) {
        const int wbase = tile * 64;
        const int nt = tile + nw;

        // ---- phase 1: a^T[j][r] = sum_k w[j][k] z[r][k] + bb[j] ----
        f32x4 acc[4];
        #pragma unroll
        for (int g = 0; g < 4; ++g) acc[g] = bbv;

        #pragma unroll
        for (int h = 0; h < 2; ++h) {
            #pragma unroll
            for (int g = 0; g < 4; ++g) {
                const float4 a4 = zA[h][g], b4 = zB[h][g];
                float z8[8] = {a4.x, a4.y, a4.z, a4.w, b4.x, b4.y, b4.z, b4.w};
                bf16x8 zhi, zlo; split8(z8, zhi, zlo);
                acc[g] = __builtin_amdgcn_mfma_f32_16x16x32_bf16(whi[h], zhi, acc[g], 0, 0, 0);
                acc[g] = __builtin_amdgcn_mfma_f32_16x16x32_bf16(wlo[h], zhi, acc[g], 0, 0, 0);
                acc[g] = __builtin_amdgcn_mfma_f32_16x16x32_bf16(whi[h], zlo, acc[g], 0, 0, 0);
            }
        }

        // ---- prefetch next tile into the (now dead) z registers ----
        if (nt < ntiles) {
            const int nb = nt * 64;
            #pragma unroll
            for (int h = 0; h < 2; ++h) {
                #pragma unroll
                for (int g = 0; g < 4; ++g) {
                    const int grow = min(nb + g * 16 + r15, n - 1);
                    const float4* p = zg + (size_t)grow * 16 + h * 8 + q;
                    zA[h][g] = p[0];
                    zB[h][g] = p[4];
                }
            }
        }

        // ---- phase 2 + outputs, per 16-row group ----
        float trs[4];
        #pragma unroll
        for (int g = 0; g < 4; ++g) {
            const float t0 = fast_tanh(acc[g][0]);
            const float t1 = fast_tanh(acc[g][1]);
            const float t2 = fast_tanh(acc[g][2]);
            const float t3 = fast_tanh(acc[g][3]);

            float tr = (1.0f - t0 * t0) * nuwv[0];
            tr = fmaf(1.0f - t1 * t1, nuwv[1], tr);
            tr = fmaf(1.0f - t2 * t2, nuwv[2], tr);
            tr = fmaf(1.0f - t3 * t3, nuwv[3], tr);
            tr += __shfl_xor(tr, 16);
            tr += __shfl_xor(tr, 32);
            trs[g] = tr;

            // th -> B-frag: lane needs th[j = q*8+e][r15] from quadrants 2q, 2q+1
            const int pk01 = (int)cvt_pk_bf16(t0, t1);
            const int pk23 = (int)cvt_pk_bf16(t2, t3);
            const int w0 = __shfl(pk01, sbase);
            const int w1 = __shfl(pk23, sbase);
            const int w2 = __shfl(pk01, sbase + 16);
            const int w3 = __shfl(pk23, sbase + 16);
            const bool act = (q < 2);
            U4 B;
            B.u[0] = act ? (unsigned)w0 : 0u;
            B.u[1] = act ? (unsigned)w1 : 0u;
            B.u[2] = act ? (unsigned)w2 : 0u;
            B.u[3] = act ? (unsigned)w3 : 0u;
            const bf16x8 b2 = B.v;

            f32x4 o[4];
            #pragma unroll
            for (int dt = 0; dt < 4; ++dt) {
                f32x4 zz = {0.f, 0.f, 0.f, 0.f};
                zz    = __builtin_amdgcn_mfma_f32_16x16x32_bf16(ulo[dt], b2, zz, 0, 0, 0);
                o[dt] = __builtin_amdgcn_mfma_f32_16x16x32_bf16(uhi[dt], b2, zz, 0, 0, 0);
            }
            // stores: lane holds dz[row = wbase+g*16+r15][d = dt*16+4q .. +3]
            const int grow = wbase + g * 16 + r15;
            if (grow < n) {
                #pragma unroll
                for (int dt = 0; dt < 4; ++dt) {
                    float4 s = make_float4(o[dt][0], o[dt][1], o[dt][2], o[dt][3]);
                    dzv[(size_t)grow * 16 + dt * 4 + q] = s;
                }
            }
        }

        // dlog: lane l -> group q, in-group row r15
        float trf = trs[0];
        trf = (q == 1) ? trs[1] : trf;
        trf = (q == 2) ? trs[2] : trf;
        trf = (q == 3) ? trs[3] : trf;
        if (wbase + l < n) dlog[wbase + l] = trf;

        if (nt >= ntiles) break;
        tile = nt;
    }
}

extern "C" void kernel_launch(void* const* d_in, const int* in_sizes, int n_in,
                              void* d_out, int out_size, void* d_ws, size_t ws_size,
                              hipStream_t stream) {
    const float* t  = (const float*)d_in[0];
    const float* z  = (const float*)d_in[1];
    const float* W1 = (const float*)d_in[2];
    const float* b1 = (const float*)d_in[3];
    const float* W2 = (const float*)d_in[4];
    const float* b2 = (const float*)d_in[5];
    const float* W3 = (const float*)d_in[6];
    const float* b3 = (const float*)d_in[7];

    const int n = in_sizes[1] / IO_DIM;   // 500000
    float* ws   = (float*)d_ws;
    float* out  = (float*)d_out;
    float* dzp  = out;
    float* dlog = out + (size_t)n * IO_DIM;

    cnf_prep<<<17, 128, 0, stream>>>(t, W1, b1, W2, b2, W3, b3, ws);

    const int ntiles = (n + 63) >> 6;
    int grid = GRID_PERSIST;
    const int max_blocks = (ntiles + (NTH / 64) - 1) / (NTH / 64);
    if (grid > max_blocks) grid = max_blocks;
    cnf_main<<<grid, NTH, 0, stream>>>(z, ws, dzp, dlog, n);
}